// Round 8
// baseline (218.805 us; speedup 1.0000x reference)
//
#include <hip/hip_runtime.h>

// Problem: B=64, H=W=512 fp32. out = x + (f - conv3x3(x,k_b)) / 6, zero pad,
// cross-correlation (no kernel flip).
//
// R11 (post-mortem of R10): cutting VMEM bytes 335->213 MB changed nothing;
// per-CU VMEM rate across rounds (24.5/21/14.7/13.4 GB/s for R4/R9/R8/R10)
// tracks the fraction of wave lifetime spent with loads OUTSTANDING, not
// bytes. All previous designs are burst-then-drain: load, then idle the VMEM
// queue through shfl/compute/barrier. Fix is structural:
//  - Persistent 4-row-strip waves (8192), NO barriers, NO LDS.
//  - 2-stage register pipeline: while computing row cur, the 4 quad-loads of
//    row cur+1 (x and f) are in flight, issued above the compute and pinned
//    by sched_barrier(0). Every resident wave keeps loads outstanding for
//    its whole life -> sustained queue occupancy (the m13 copy-bench
//    structure, which is how 6.3 TB/s is actually achieved).
//  - Sliding window keeps halos as Q structs: only 6 new shfls per row
//    (vs 18 in R9/R10); x rows re-read ~1.25x instead of 3x.
//  - R9-proven parts kept: split-quad ownership (contiguous 1024B footprint
//    per load AND store -> WRITE_SIZE exactly 65536 KB), shfl-only halos,
//    clamp-address + zero-weight row edges (straight-line waves).
//  - readfirstlane(i0) -> row indices SGPR -> weight selects stay scalar.
#define BB 64
#define HH 512
#define WW 512
#define LROWS 4                       // rows per wave strip
#define NBLOCKS (BB * HH / LROWS / 4) // 2048 blocks * 4 waves = 8192 strips

struct Q { float4 v; float l, r; };   // quad + left/right halo floats

// cross-correlation accumulate: (w0,w1,w2) multiply cols j-1,j,j+1
__device__ __forceinline__ void accumq(float4& q, const Q& w,
                                       float w0, float w1, float w2) {
    q.x += w0 * w.l   + w1 * w.v.x + w2 * w.v.y;
    q.y += w0 * w.v.x + w1 * w.v.y + w2 * w.v.z;
    q.z += w0 * w.v.y + w1 * w.v.z + w2 * w.v.w;
    q.w += w0 * w.v.z + w1 * w.v.w + w2 * w.r;
}

// build halo-extended quads for one row from its two raw quads
__device__ __forceinline__ void mkhalo(Q& A, Q& Bq, const float4 a,
                                       const float4 bv, int lane) {
    const float a_l  = __shfl_up(a.w, 1);
    const float a_r  = __shfl_down(a.x, 1);
    const float b_l  = __shfl_up(bv.w, 1);
    const float b_r  = __shfl_down(bv.x, 1);
    const float aw63 = __shfl(a.w, 63);            // float[255]
    const float bx0  = __shfl(bv.x, 0);            // float[256]
    A.v  = a;
    Bq.v = bv;
    A.l  = (lane == 0)  ? 0.f  : a_l;              // image left edge pad
    A.r  = (lane == 63) ? bx0  : a_r;              // col 256 from quad B
    Bq.l = (lane == 0)  ? aw63 : b_l;              // col 255 from quad A
    Bq.r = (lane == 63) ? 0.f  : b_r;              // image right edge pad
}

__global__ __launch_bounds__(256, 6) void jacobi_v11_kernel(
    const float* __restrict__ x,
    const float* __restrict__ f,
    const float* __restrict__ k,
    float* __restrict__ out)
{
    const int tid  = threadIdx.x;
    const int lane = tid & 63;
    const int wv   = tid >> 6;

    // 32 blocks per image -> b scalar (SGPR) by construction.
    const int b  = blockIdx.x >> 5;
    // strip start row; wave-uniform -> force SGPR so weight selects are scalar
    const int i0 = __builtin_amdgcn_readfirstlane(
                       ((((blockIdx.x & 31) << 2) + wv) << 2));

    const size_t img = (size_t)b * (HH * WW);
    const float* xb = x + img;
    const float* fb = f + img;
    float*       ob = out + img;

    const float* kb = k + b * 9;                   // scalar -> s_load
    const float k00 = kb[0], k01 = kb[1], k02 = kb[2];
    const float k10 = kb[3], k11 = kb[4], k12 = kb[5];
    const float k20 = kb[6], k21 = kb[7], k22 = kb[8];

    const int col = lane << 2;                     // quad A col; quad B = +256

    // ---- pipeline fill: x rows i0-1(clamped), i0, i0+1; f(i0); plus the
    // first prefetch pair x(i0+2 clamped), f(i0+1). 12 loads back-to-back.
    const int rm = (i0 > 0) ? i0 - 1 : 0;
    const int rn = (i0 + 2 < HH) ? i0 + 2 : HH - 1;
    const float* pm = xb + (size_t)rm * WW + col;
    const float* pc = xb + (size_t)i0 * WW + col;
    const float* pp = pc + WW;                     // i0+1 (strips are interior)
    const float* pn = xb + (size_t)rn * WW + col;
    const float* pf = fb + (size_t)i0 * WW + col;
    const float4 xma = *(const float4*)pm, xmb = *(const float4*)(pm + 256);
    const float4 xca = *(const float4*)pc, xcb = *(const float4*)(pc + 256);
    const float4 xpa = *(const float4*)pp, xpb = *(const float4*)(pp + 256);
    float4 fca = *(const float4*)pf,       fcb = *(const float4*)(pf + 256);
    float4 xna = *(const float4*)pn,       xnb = *(const float4*)(pn + 256);
    float4 fna = *(const float4*)(pf + WW), fnb = *(const float4*)(pf + WW + 256);
    __builtin_amdgcn_sched_barrier(0);             // loads stay above

    // halo-extended sliding window (3 rows)
    Q Am, Bm, Ac, Bc, Ap, Bp;
    mkhalo(Am, Bm, xma, xmb, lane);
    mkhalo(Ac, Bc, xca, xcb, lane);
    mkhalo(Ap, Bp, xpa, xpb, lane);

    const float inv6 = 1.f / 6.f;
    #pragma unroll
    for (int r = 0; r < LROWS; ++r) {
        const int cur = i0 + r;                    // SGPR-uniform
        if (r > 0) {
            // slide window (halos already built for these rows)
            Am = Ac; Bm = Bc;
            Ac = Ap; Bc = Bp;
            mkhalo(Ap, Bp, xna, xnb, lane);        // waits on prev prefetch
            fca = fna; fcb = fnb;
            if (r < LROWS - 1) {
                // issue next prefetch (consumed at iter r+1)
                const int nx = (cur + 2 < HH) ? cur + 2 : HH - 1;
                const float* px = xb + (size_t)nx * WW + col;
                const float* pg = fb + (size_t)(cur + 1) * WW + col;
                xna = *(const float4*)px; xnb = *(const float4*)(px + 256);
                fna = *(const float4*)pg; fnb = *(const float4*)(pg + 256);
            }
            __builtin_amdgcn_sched_barrier(0);     // prefetch above compute
        }

        // row-edge weight zeroing (scalar selects; cur is SGPR)
        const float w00 = (cur > 0)      ? k00 : 0.f;
        const float w01 = (cur > 0)      ? k01 : 0.f;
        const float w02 = (cur > 0)      ? k02 : 0.f;
        const float w20 = (cur < HH - 1) ? k20 : 0.f;
        const float w21 = (cur < HH - 1) ? k21 : 0.f;
        const float w22 = (cur < HH - 1) ? k22 : 0.f;

        float4 qa = make_float4(0.f, 0.f, 0.f, 0.f);
        float4 qb = make_float4(0.f, 0.f, 0.f, 0.f);
        accumq(qa, Am, w00, w01, w02);             // stencil row cur-1
        accumq(qa, Ac, k10, k11, k12);             // stencil row cur
        accumq(qa, Ap, w20, w21, w22);             // stencil row cur+1
        accumq(qb, Bm, w00, w01, w02);
        accumq(qb, Bc, k10, k11, k12);
        accumq(qb, Bp, w20, w21, w22);

        float4 oa, oq;
        oa.x = Ac.v.x + (fca.x - qa.x) * inv6;
        oa.y = Ac.v.y + (fca.y - qa.y) * inv6;
        oa.z = Ac.v.z + (fca.z - qa.z) * inv6;
        oa.w = Ac.v.w + (fca.w - qa.w) * inv6;
        oq.x = Bc.v.x + (fcb.x - qb.x) * inv6;
        oq.y = Bc.v.y + (fcb.y - qb.y) * inv6;
        oq.z = Bc.v.z + (fcb.z - qb.z) * inv6;
        oq.w = Bc.v.w + (fcb.w - qb.w) * inv6;

        float* po = ob + (size_t)cur * WW + col;
        *(float4*)po         = oa;                 // contiguous 1024 B
        *(float4*)(po + 256) = oq;                 // contiguous 1024 B
    }
}

extern "C" void kernel_launch(void* const* d_in, const int* in_sizes, int n_in,
                              void* d_out, int out_size, void* d_ws, size_t ws_size,
                              hipStream_t stream) {
    const float* x  = (const float*)d_in[0];
    const float* f  = (const float*)d_in[1];
    const float* kk = (const float*)d_in[2];
    float* out = (float*)d_out;

    jacobi_v11_kernel<<<NBLOCKS, 256, 0, stream>>>(x, f, kk, out);
}

// Round 10
// 179.727 us; speedup vs baseline: 1.2174x; 1.2174x over previous
//
#include <hip/hip_runtime.h>

// Problem: B=64, H=W=512 fp32. out = x + (f - conv3x3(x,k_b)) / 6, zero pad,
// cross-correlation (no kernel flip).
//
// R12 = R4 (the 57.5us champion: one output quad per thread, max TLP) plus
// ONE change: bijective XCD-aware blockIdx swizzle.
// Post-mortems R8-R11 established: byte-reduction designs (LDS tile, fat
// waves, sliding window) all lose because they trade away VMEM-queue
// concurrency (R11 additionally spilled to scratch: WRITE_SIZE 3.3x).
// The kernel is latency x concurrency bound. R4's mapping round-robins
// row-neighbor blocks (which re-read the same x rows) onto DIFFERENT XCDs,
// so re-reads are served at L3/remote latency (~600cy). Swizzle gives each
// XCD a contiguous 2048-block slab (= 8 whole images): all 3x row re-reads
// become same-XCD, streaming window ~100s of KB << 4MB L2 -> L2-hit latency
// (~200cy) -> more throughput at the same in-flight byte budget.
// (Resubmitted verbatim after an infra-only failure: "MI355X container
// failed twice" — kernel never ran.)
#define BB 64
#define HH 512
#define WW 512
#define W4 (WW / 4)

struct RowE { float4 v; float l, r; };  // quad + left/right halo floats

__device__ __forceinline__ RowE load_row(const float* __restrict__ xrow,
                                         int j0, int lane) {
    RowE r;
    r.v = *(const float4*)(xrow + j0);
    // neighbor-lane halos (all lanes participate in the shuffles)
    float lh = __shfl_up(r.v.w, 1);
    float rh = __shfl_down(r.v.x, 1);
    // wave-edge lanes: neighbor quad lives in another wave -> masked load
    if (lane == 0)  lh = (j0 > 0)      ? xrow[j0 - 1] : 0.f;
    if (lane == 63) rh = (j0 + 4 < WW) ? xrow[j0 + 4] : 0.f;
    r.l = lh; r.r = rh;
    return r;
}

__device__ __forceinline__ RowE zero_row() {
    RowE r;
    r.v = make_float4(0.f, 0.f, 0.f, 0.f);
    r.l = 0.f; r.r = 0.f;
    return r;
}

__global__ __launch_bounds__(256) void jacobi_v12_kernel(
    const float* __restrict__ x,
    const float* __restrict__ f,
    const float* __restrict__ k,
    float* __restrict__ out)
{
    const int tid  = threadIdx.x;
    const int lane = tid & 63;

    // XCD swizzle: dispatch id d lands on XCD d%8 (8 XCDs). Remap so XCD k
    // runs the contiguous logical slab [k*2048, (k+1)*2048) = 8 whole images:
    // row-neighbor blocks (which share x rows) execute on the SAME XCD.
    // nwg = 16384 = 8 * 2048 -> bijective.
    const int orig = blockIdx.x;
    const int bid  = ((orig & 7) << 11) + (orig >> 3);

    // 256 blocks per image -> b is scalar (SGPR) by construction.
    const int b = bid >> 8;
    const int q = ((bid & 255) << 8) + tid;         // quad index within image
    const int j4 = q & (W4 - 1);                    // wave-contiguous
    const int i  = q >> 7;                          // row, wave-uniform
    const int j0 = j4 << 2;

    const size_t img = (size_t)b * HH * WW;
    const float* xb = x + img;

    const float* kb = k + b * 9;  // scalar -> s_load
    const float k00 = kb[0], k01 = kb[1], k02 = kb[2];
    const float k10 = kb[3], k11 = kb[4], k12 = kb[5];
    const float k20 = kb[6], k21 = kb[7], k22 = kb[8];

    // three stencil rows (i-1, i, i+1); i is wave-uniform so the edge
    // branches are non-divergent.
    const RowE c = load_row(xb + (size_t)i * WW, j0, lane);
    const RowE m = (i > 0)      ? load_row(xb + (size_t)(i - 1) * WW, j0, lane)
                                : zero_row();
    const RowE p = (i < HH - 1) ? load_row(xb + (size_t)(i + 1) * WW, j0, lane)
                                : zero_row();

    // cross-correlation: k[r][cc] multiplies x[i+r-1][j+cc-1]
    float4 acc;
    acc.x = k00 * m.l   + k01 * m.v.x + k02 * m.v.y
          + k10 * c.l   + k11 * c.v.x + k12 * c.v.y
          + k20 * p.l   + k21 * p.v.x + k22 * p.v.y;
    acc.y = k00 * m.v.x + k01 * m.v.y + k02 * m.v.z
          + k10 * c.v.x + k11 * c.v.y + k12 * c.v.z
          + k20 * p.v.x + k21 * p.v.y + k22 * p.v.z;
    acc.z = k00 * m.v.y + k01 * m.v.z + k02 * m.v.w
          + k10 * c.v.y + k11 * c.v.z + k12 * c.v.w
          + k20 * p.v.y + k21 * p.v.z + k22 * p.v.w;
    acc.w = k00 * m.v.z + k01 * m.v.w + k02 * m.r
          + k10 * c.v.z + k11 * c.v.w + k12 * c.r
          + k20 * p.v.z + k21 * p.v.w + k22 * p.r;

    const size_t idx4 = (size_t)b * HH * W4 + (size_t)i * W4 + j4;
    const float4 fv = ((const float4*)f)[idx4];

    const float inv6 = 1.f / 6.f;
    float4 o;
    o.x = c.v.x + (fv.x - acc.x) * inv6;
    o.y = c.v.y + (fv.y - acc.y) * inv6;
    o.z = c.v.z + (fv.z - acc.z) * inv6;
    o.w = c.v.w + (fv.w - acc.w) * inv6;

    ((float4*)out)[idx4] = o;
}

extern "C" void kernel_launch(void* const* d_in, const int* in_sizes, int n_in,
                              void* d_out, int out_size, void* d_ws, size_t ws_size,
                              hipStream_t stream) {
    const float* x = (const float*)d_in[0];
    const float* f = (const float*)d_in[1];
    const float* kk = (const float*)d_in[2];
    float* out = (float*)d_out;

    const int blocks = (BB * HH * W4) / 256;  // 16384
    jacobi_v12_kernel<<<blocks, 256, 0, stream>>>(x, f, kk, out);
}